// Round 1
// baseline (911.423 us; speedup 1.0000x reference)
//
#include <hip/hip_runtime.h>

// out[B,64] = x[B,64] @ W[:, :64]^T + b   (W stored [64][128] row-major, fp32)
//
// Mapping: lane h (0..63) owns output column h and holds W[h][0:64] in 64 VGPRs.
// Each wave processes tiles of 8 rows: stage 8*64 fp32 into per-wave LDS with
// two coalesced float4 loads per lane, then broadcast-read x values (wave-
// uniform LDS addresses -> conflict-free) against the register-resident W.
// Stores are 256B coalesced (lane h -> col h of a contiguous row).
//
// B = 2^21 -> 262144 tiles / 4096 waves = exactly 64 iterations per wave,
// uniform across the block, so the in-loop __syncthreads() cannot deadlock.

#define ROWS_PER_TILE 8

__global__ __launch_bounds__(256, 4)
void hmsrl_kernel(const float* __restrict__ x, const float* __restrict__ W,
                  const float* __restrict__ b, float* __restrict__ out, int B) {
    __shared__ float xbuf[4][ROWS_PER_TILE * 64];   // 2 KB per wave, 8 KB/block

    const int lane = threadIdx.x & 63;
    const int wv   = threadIdx.x >> 6;

    // --- W row for this lane's output column: 16 x float4 = 64 VGPRs ---
    const float4* wrow = reinterpret_cast<const float4*>(W + lane * 128);
    float4 wreg[16];
    #pragma unroll
    for (int j = 0; j < 16; ++j) wreg[j] = wrow[j];
    const float bias = b[lane];

    const int wave_global = blockIdx.x * 4 + wv;
    const int num_waves   = gridDim.x * 4;
    const int total_tiles = B / ROWS_PER_TILE;

    const float4* x4   = reinterpret_cast<const float4*>(x);
    float4* lbuf4      = reinterpret_cast<float4*>(xbuf[wv]);

    for (int tile = wave_global; tile < total_tiles; tile += num_waves) {
        // ---- stage 8 rows (512 floats = 128 float4) into LDS, coalesced ----
        const long base4 = (long)tile * 128;
        float4 v0 = x4[base4 + lane];
        float4 v1 = x4[base4 + 64 + lane];
        __syncthreads();                    // previous iter's reads done
        lbuf4[lane]      = v0;
        lbuf4[64 + lane] = v1;
        __syncthreads();                    // writes visible

        // ---- compute: acc[r] = b[h] + sum_k x[r][k] * W[h][k] ----
        float acc[ROWS_PER_TILE];
        #pragma unroll
        for (int r = 0; r < ROWS_PER_TILE; ++r) acc[r] = bias;

        #pragma unroll
        for (int k4 = 0; k4 < 16; ++k4) {
            const float4 wvreg = wreg[k4];
            #pragma unroll
            for (int r = 0; r < ROWS_PER_TILE; ++r) {
                const float4 xv = lbuf4[r * 16 + k4];   // wave-uniform addr -> broadcast
                acc[r] = fmaf(xv.x, wvreg.x, acc[r]);
                acc[r] = fmaf(xv.y, wvreg.y, acc[r]);
                acc[r] = fmaf(xv.z, wvreg.z, acc[r]);
                acc[r] = fmaf(xv.w, wvreg.w, acc[r]);
            }
        }

        // ---- store: 256 B coalesced per row ----
        float* orow = out + (long)tile * (ROWS_PER_TILE * 64);
        #pragma unroll
        for (int r = 0; r < ROWS_PER_TILE; ++r) {
            orow[r * 64 + lane] = acc[r];
        }
    }
}

extern "C" void kernel_launch(void* const* d_in, const int* in_sizes, int n_in,
                              void* d_out, int out_size, void* d_ws, size_t ws_size,
                              hipStream_t stream) {
    const float* x = (const float*)d_in[0];
    const float* W = (const float*)d_in[1];
    const float* b = (const float*)d_in[2];
    float* out     = (float*)d_out;

    const int B = in_sizes[0] / 64;     // 2,097,152

    hmsrl_kernel<<<1024, 256, 0, stream>>>(x, W, b, out, B);
}